// Round 14
// baseline (263.748 us; speedup 1.0000x reference)
//
#include <hip/hip_runtime.h>
#include <cstddef>

#define T_LEN 1000
#define B_SZ 64
#define C_IN_ 12
#define D_MODEL_ 128
#define D_INNER_ 256
#define D_STATE_ 16
#define DT_RANK_ 8
#define N_CLS 5
#define NCH 5       // scan time-chunks (200 steps each)
#define CT8 25      // 8-step iterations per chunk

typedef __attribute__((ext_vector_type(8))) short bf16x8;
typedef __attribute__((ext_vector_type(8))) unsigned short u16x8;
typedef __attribute__((ext_vector_type(4))) float f32x4;

__device__ __forceinline__ float fast_exp2(float x) {
#if __has_builtin(__builtin_amdgcn_exp2f)
  return __builtin_amdgcn_exp2f(x);
#else
  float r; asm volatile("v_exp_f32 %0, %1" : "=v"(r) : "v"(x)); return r;
#endif
}
__device__ __forceinline__ float fast_log2(float x) {
#if __has_builtin(__builtin_amdgcn_logf)
  return __builtin_amdgcn_logf(x);
#else
  float r; asm volatile("v_log_f32 %0, %1" : "=v"(r) : "v"(x)); return r;
#endif
}
__device__ __forceinline__ float fast_rcp(float x) {
#if __has_builtin(__builtin_amdgcn_rcpf)
  return __builtin_amdgcn_rcpf(x);
#else
  float r; asm volatile("v_rcp_f32 %0, %1" : "=v"(r) : "v"(x)); return r;
#endif
}
__device__ __forceinline__ float silu_f(float x) {
  float den = 1.f + fast_exp2(-x * 1.4426950408889634f);
  return x * fast_rcp(den);
}
__device__ __forceinline__ float softplus_f(float x) {
  const float L = 1.4426950408889634f, iL = 0.6931471805599453f;
  float e = fast_exp2(-fabsf(x) * L);
  float l = fast_log2(1.f + e) * iL;
  return fmaxf(x, 0.f) + l;
}
__device__ __forceinline__ unsigned short f2bf(float f) {
  unsigned u = __builtin_bit_cast(unsigned, f);
  u = u + 0x7FFFu + ((u >> 16) & 1u);   // RNE
  return (unsigned short)(u >> 16);
}
__device__ __forceinline__ float bf2f(unsigned short h) {
  unsigned u = ((unsigned)h) << 16;
  return __builtin_bit_cast(float, u);
}

// K0: h = x@ip_w.T + ip_b (bf16, MFMA-frag-packed, zero-filled t>=1000) + W pack.
__global__ __launch_bounds__(256) void k0_prep(
    const float* __restrict__ x, const float* __restrict__ ip_w,
    const float* __restrict__ ip_b, const float* __restrict__ in_proj_w,
    char* __restrict__ h_pk, char* __restrict__ w_pk)
{
  __shared__ unsigned short pk_s[8192];
  __shared__ unsigned short pkw_s[32768];
  const int tid = threadIdx.x;

  if (blockIdx.x == 16) {                    // W-pack block
    if (blockIdx.y != 0) return;
    const int n = tid;
    for (int k = 0; k < D_MODEL_; ++k) {
      unsigned short v = f2bf(in_proj_w[(size_t)n * D_MODEL_ + k]);
      int off = ((n >> 4) * 4 + (k >> 5)) * 512 + ((k & 31) >> 3) * 128
              + (n & 15) * 8 + (k & 7);
      pkw_s[off] = v;
    }
    __syncthreads();
    const float4* s4 = (const float4*)pkw_s;
    float4* dst = (float4*)w_pk;
#pragma unroll
    for (int q = 0; q < 16; ++q) dst[tid * 16 + q] = s4[tid * 16 + q];
    return;
  }

  const int tile4 = blockIdx.x;
  const int b = blockIdx.y;
  const int rl = tid & 63;
  const int kc = (tid >> 6) * 32;
  const int t = tile4 * 64 + rl;

  float xr[C_IN_] = {0.f, 0.f, 0.f, 0.f, 0.f, 0.f, 0.f, 0.f, 0.f, 0.f, 0.f, 0.f};
  const bool valid = (t < T_LEN);
  if (valid) {
    const float4* xp = (const float4*)(x + ((size_t)b * T_LEN + t) * C_IN_);
    float4 v0 = xp[0], v1 = xp[1], v2 = xp[2];
    xr[0] = v0.x; xr[1] = v0.y; xr[2] = v0.z;  xr[3] = v0.w;
    xr[4] = v1.x; xr[5] = v1.y; xr[6] = v1.z;  xr[7] = v1.w;
    xr[8] = v2.x; xr[9] = v2.y; xr[10] = v2.z; xr[11] = v2.w;
  }
  for (int kk = 0; kk < 32; ++kk) {
    const int k = kc + kk;
    unsigned short v = 0;
    if (valid) {
      float acc = ip_b[k];
      const float* wr = ip_w + k * C_IN_;
#pragma unroll
      for (int c = 0; c < C_IN_; ++c) acc += xr[c] * wr[c];
      v = f2bf(acc);
    }
    int off = (rl >> 4) * 2048 + (k >> 5) * 512 + ((k & 31) >> 3) * 128
            + (rl & 15) * 8 + (k & 7);
    pk_s[off] = v;
  }
  __syncthreads();
  const float4* s4 = (const float4*)pk_s;
  float4* dst = (float4*)(h_pk + (size_t)(b * 64 + tile4 * 4) * 4096);
#pragma unroll
  for (int q = 0; q < 4; ++q) dst[tid * 4 + q] = s4[tid * 4 + q];
}

// K1 FUSED: MFMA xm GEMM -> conv+silu writes u IN-PLACE into xm LDS rows
// (row i dead after conv step i; each thread owns one column -> race-free)
// -> phase1 dbc GEMM (K=256 from LDS) -> phase2 softplus + packed emission.
// u never touches HBM; old k3 eliminated.
__global__ __launch_bounds__(256) void k1_fused(
    const char* __restrict__ h_pk, const char* __restrict__ w_pk,
    const float* __restrict__ conv_w, const float* __restrict__ conv_b,
    const float* __restrict__ x_proj_w, const float* __restrict__ dt_proj_w,
    const float* __restrict__ dt_proj_b,
    float* __restrict__ pk_delta, float* __restrict__ pk_du,
    float* __restrict__ pk_bm, float* __restrict__ u_last)
{
  __shared__ float xm[67][260];    // xm tile, then reused as u tile (rows 0..63)
  __shared__ float dt_s[64][9];
  __shared__ float bm_s[64][17];

  const int tile = blockIdx.x;     // 0..15, t0 = tile*64
  const int b    = blockIdx.y;
  const int t0   = tile * 64;
  const int tid  = threadIdx.x;
  const int w    = tid >> 6;
  const int l    = tid & 63;

  const float4 w0 = *(const float4*)&dt_proj_w[(size_t)tid * 8];
  const float4 w1 = *(const float4*)&dt_proj_w[(size_t)tid * 8 + 4];
  const float bias = dt_proj_b[tid];

  // --- MFMA phase: xm rows 3..66 = t0..t0+63 ---
  {
    const char* achunk = h_pk + (size_t)(b * 64 + tile * 4 + w) * 4096;
    bf16x8 a0 = *(const bf16x8*)(achunk + 0 * 1024 + l * 16);
    bf16x8 a1 = *(const bf16x8*)(achunk + 1 * 1024 + l * 16);
    bf16x8 a2 = *(const bf16x8*)(achunk + 2 * 1024 + l * 16);
    bf16x8 a3 = *(const bf16x8*)(achunk + 3 * 1024 + l * 16);

    const int row_l = w * 16 + (l >> 4) * 4;
#pragma unroll
    for (int nt = 0; nt < 16; ++nt) {
      const char* wb = w_pk + (size_t)nt * 4096 + l * 16;
      bf16x8 b0 = *(const bf16x8*)(wb + 0 * 1024);
      bf16x8 b1 = *(const bf16x8*)(wb + 1 * 1024);
      bf16x8 b2 = *(const bf16x8*)(wb + 2 * 1024);
      bf16x8 b3 = *(const bf16x8*)(wb + 3 * 1024);
      f32x4 acc = {0.f, 0.f, 0.f, 0.f};
      acc = __builtin_amdgcn_mfma_f32_16x16x32_bf16(a0, b0, acc, 0, 0, 0);
      acc = __builtin_amdgcn_mfma_f32_16x16x32_bf16(a1, b1, acc, 0, 0, 0);
      acc = __builtin_amdgcn_mfma_f32_16x16x32_bf16(a2, b2, acc, 0, 0, 0);
      acc = __builtin_amdgcn_mfma_f32_16x16x32_bf16(a3, b3, acc, 0, 0, 0);
      const int col = nt * 16 + (l & 15);
#pragma unroll
      for (int r = 0; r < 4; ++r)
        xm[3 + row_l + r][col] = acc[r];
    }
  }

  // --- halo rows t0-3..t0-1 ---
  {
    const int n = tid;
    float hac[3] = {0.f, 0.f, 0.f};
    if (tile > 0) {
      const char* wrow = w_pk + (size_t)(n >> 4) * 4096 + (n & 15) * 16;
#pragma unroll
      for (int kt = 0; kt < 4; ++kt)
#pragma unroll
        for (int lg = 0; lg < 4; ++lg) {
          u16x8 wv = *(const u16x8*)(wrow + kt * 1024 + lg * 256);
#pragma unroll
          for (int r = 0; r < 3; ++r) {
            const int t = t0 - 3 + r;
            const char* hc = h_pk + (size_t)(b * 64 + (t >> 4)) * 4096;
            u16x8 hv = *(const u16x8*)(hc + kt * 1024 + lg * 256 + (t & 15) * 16);
#pragma unroll
            for (int j = 0; j < 8; ++j) hac[r] += bf2f(hv[j]) * bf2f(wv[j]);
          }
        }
    }
#pragma unroll
    for (int r = 0; r < 3; ++r) xm[r][n] = hac[r];
  }
  __syncthreads();

  // --- conv + silu, u written IN-PLACE to xm[i][n] (column-private) ---
  {
    const int n = tid;
    const float4 cw = *(const float4*)&conv_w[n * 4];
    const float  cb = conv_b[n];
    float x0 = xm[0][n], x1 = xm[1][n], x2 = xm[2][n];
    for (int i = 0; i < 64; ++i) {
      float x3 = xm[3 + i][n];
      float s = cb + x0 * cw.x + x1 * cw.y + x2 * cw.z + x3 * cw.w;
      float uv = silu_f(s);
      xm[i][n] = uv;                 // row i never read again by this thread
      if (t0 + i == T_LEN - 1) u_last[b * 256 + n] = uv;
      x0 = x1; x1 = x2; x2 = x3;
    }
  }
  __syncthreads();

  // --- phase 1: dbc = u_tile @ xp[0:24].T  (u rows 0..63 in LDS) ---
  {
    const int r2 = tid >> 3, cg = tid & 7;
    const int ra = 2 * r2;
    const float4* ua4 = (const float4*)&xm[ra][0];
    const float4* ub4 = (const float4*)&xm[ra + 1][0];
    float a0 = 0.f, a1 = 0.f, a2 = 0.f, b0 = 0.f, b1 = 0.f, b2 = 0.f;
    const float4* q0p = (const float4*)&x_proj_w[(size_t)(cg * 3 + 0) * 256];
    const float4* q1p = (const float4*)&x_proj_w[(size_t)(cg * 3 + 1) * 256];
    const float4* q2p = (const float4*)&x_proj_w[(size_t)(cg * 3 + 2) * 256];
    for (int k4 = 0; k4 < 64; ++k4) {
      float4 a = ua4[k4], bb = ub4[k4];
      float4 q0 = q0p[k4], q1 = q1p[k4], q2 = q2p[k4];
      a0 += a.x * q0.x + a.y * q0.y + a.z * q0.z + a.w * q0.w;
      a1 += a.x * q1.x + a.y * q1.y + a.z * q1.z + a.w * q1.w;
      a2 += a.x * q2.x + a.y * q2.y + a.z * q2.z + a.w * q2.w;
      b0 += bb.x * q0.x + bb.y * q0.y + bb.z * q0.z + bb.w * q0.w;
      b1 += bb.x * q1.x + bb.y * q1.y + bb.z * q1.z + bb.w * q1.w;
      b2 += bb.x * q2.x + bb.y * q2.y + bb.z * q2.z + bb.w * q2.w;
    }
    float va[2][3] = {{a0, a1, a2}, {b0, b1, b2}};
#pragma unroll
    for (int rr = 0; rr < 2; ++rr)
#pragma unroll
      for (int c = 0; c < 3; ++c) {
        int col = cg * 3 + c;
        int row = ra + rr;
        if (col < 8) dt_s[row][col] = va[rr][c];
        else bm_s[row][col - 8] = va[rr][c];
      }
  }
  __syncthreads();

  // --- phase 2: thread = d; softplus + packed delta/du emission ---
  for (int g = 0; g < 8; ++g) {
    if (t0 + g * 8 >= T_LEN) break;      // tile 15 tail (t>=1000)
    float dd[8], uu[8];
#pragma unroll
    for (int j = 0; j < 8; ++j) {
      int r = g * 8 + j;
      float pre = bias
        + dt_s[r][0] * w0.x + dt_s[r][1] * w0.y + dt_s[r][2] * w0.z + dt_s[r][3] * w0.w
        + dt_s[r][4] * w1.x + dt_s[r][5] * w1.y + dt_s[r][6] * w1.z + dt_s[r][7] * w1.w;
      float dlt = softplus_f(pre);
      dd[j] = dlt;
      uu[j] = dlt * xm[r][tid];
    }
    int t = t0 + g * 8;
    size_t base = (((size_t)b * 250 + (t >> 2)) * 256 + tid) * 4;
    *(float4*)&pk_delta[base]        = make_float4(dd[0], dd[1], dd[2], dd[3]);
    *(float4*)&pk_delta[base + 1024] = make_float4(dd[4], dd[5], dd[6], dd[7]);
    *(float4*)&pk_du[base]           = make_float4(uu[0], uu[1], uu[2], uu[3]);
    *(float4*)&pk_du[base + 1024]    = make_float4(uu[4], uu[5], uu[6], uu[7]);
  }
  if (tid < 16) {
    for (int g = 0; g < 8; ++g) {
      if (t0 + g * 8 >= T_LEN) break;
      float pb[8];
#pragma unroll
      for (int j = 0; j < 8; ++j) pb[j] = bm_s[g * 8 + j][tid];
      int t = t0 + g * 8;
      size_t base = (((size_t)b * 250 + (t >> 2)) * 16 + tid) * 4;
      *(float4*)&pk_bm[base]      = make_float4(pb[0], pb[1], pb[2], pb[3]);
      *(float4*)&pk_bm[base + 64] = make_float4(pb[4], pb[5], pb[6], pb[7]);
    }
  }
}

// K4 v12: 8-step iterations (A/B named register sets, static indices) with
// 1-iteration prefetch -> 6 b128 in flight/wave (~890 cyc cover >= L3 latency).
__global__ __launch_bounds__(256) void k4_scan(
    const float* __restrict__ pk_delta, const float* __restrict__ pk_du,
    const float* __restrict__ pk_bm, const float* __restrict__ A_log,
    float* __restrict__ Qb, float* __restrict__ Pb)
{
  const int d0 = blockIdx.x * 16;
  const int b  = blockIdx.y;
  const int c  = blockIdx.z;
  const int tid = threadIdx.x;
  const int dl = tid >> 4;
  const int n  = tid & 15;
  const int d  = d0 + dl;

  const float A2 = -expf(A_log[(size_t)d * 16 + n]) * 1.4426950408889634f;
  float s = 0.f, sum = 0.f;

  const float* dp = pk_delta + ((size_t)b * 250 * 256 + d) * 4 + (size_t)c * 50 * 1024;
  const float* xp = pk_du    + ((size_t)b * 250 * 256 + d) * 4 + (size_t)c * 50 * 1024;
  const float* bp = pk_bm    + ((size_t)b * 250 * 16 + n) * 4 + (size_t)c * 50 * 64;

  float4 dA = *(const float4*)dp;
  float4 dB = *(const float4*)(dp + 1024);
  float4 xA = *(const float4*)xp;
  float4 xB = *(const float4*)(xp + 1024);
  float4 bA = *(const float4*)bp;
  float4 bB = *(const float4*)(bp + 64);

  for (int it = 0; it < CT8; ++it) {
    const int nx = (it < CT8 - 1) ? (2 * it + 2) : (2 * it);   // clamped tail
    const float* dpn = dp + (size_t)nx * 1024;
    const float* xpn = xp + (size_t)nx * 1024;
    const float* bpn = bp + (size_t)nx * 64;
    float4 dN0 = *(const float4*)dpn;
    float4 dN1 = *(const float4*)(dpn + 1024);
    float4 xN0 = *(const float4*)xpn;
    float4 xN1 = *(const float4*)(xpn + 1024);
    float4 bN0 = *(const float4*)bpn;
    float4 bN1 = *(const float4*)(bpn + 64);

    sum += (dA.x + dA.y) + (dA.z + dA.w);
    s = fast_exp2(dA.x * A2) * s + xA.x * bA.x;
    s = fast_exp2(dA.y * A2) * s + xA.y * bA.y;
    s = fast_exp2(dA.z * A2) * s + xA.z * bA.z;
    s = fast_exp2(dA.w * A2) * s + xA.w * bA.w;
    sum += (dB.x + dB.y) + (dB.z + dB.w);
    s = fast_exp2(dB.x * A2) * s + xB.x * bB.x;
    s = fast_exp2(dB.y * A2) * s + xB.y * bB.y;
    s = fast_exp2(dB.z * A2) * s + xB.z * bB.z;
    s = fast_exp2(dB.w * A2) * s + xB.w * bB.w;

    dA = dN0; dB = dN1; xA = xN0; xB = xN1; bA = bN0; bB = bN1;
  }

  const size_t o = (size_t)c * 262144 + (size_t)b * 4096 + (size_t)d0 * 16 + tid;
  Qb[o] = s;
  Pb[o] = fast_exp2(A2 * sum);
}

// K4b: fold the NCH affine transitions -> final state.
__global__ __launch_bounds__(256) void k4b_combine(
    const float* __restrict__ Qb, const float* __restrict__ Pb,
    float* __restrict__ state_out)
{
  const size_t g = (size_t)blockIdx.x * 256 + threadIdx.x;   // 1024 blocks
  float s = Qb[g];
#pragma unroll
  for (int c = 1; c < NCH; ++c)
    s = Qb[(size_t)c * 262144 + g] + Pb[(size_t)c * 262144 + g] * s;
  state_out[g] = s;
}

// K5: per-batch head.
__global__ __launch_bounds__(256) void k5_head(
    const float* __restrict__ x, const float* __restrict__ ip_w,
    const float* __restrict__ ip_b, const float* __restrict__ in_proj_w,
    const float* __restrict__ x_proj_w, const float* __restrict__ u_last,
    const float* __restrict__ state, const float* __restrict__ D_skip,
    const float* __restrict__ out_proj_w, const float* __restrict__ fc1_w,
    const float* __restrict__ fc1_b, const float* __restrict__ fc2_w,
    const float* __restrict__ fc2_b, float* __restrict__ out)
{
  const int b = blockIdx.x, tid = threadIdx.x;
  __shared__ float hl[128], ul[256], zs[256], cm[16], yv[256], ov[128], hid[64];
  if (tid < 128) {
    float acc = ip_b[tid];
    const float* xr = x + ((size_t)b * T_LEN + (T_LEN - 1)) * C_IN_;
#pragma unroll
    for (int c = 0; c < C_IN_; ++c) acc += xr[c] * ip_w[tid * C_IN_ + c];
    hl[tid] = acc;
  }
  ul[tid] = u_last[b * 256 + tid];
  __syncthreads();
  {
    float acc = 0.f;
    const float4* wv = (const float4*)(in_proj_w + (size_t)(256 + tid) * 128);
    const float4* h4 = (const float4*)hl;
    for (int k = 0; k < 32; ++k) {
      float4 a = wv[k], c = h4[k];
      acc += c.x * a.x + c.y * a.y + c.z * a.z + c.w * a.w;
    }
    zs[tid] = silu_f(acc);
  }
  if (tid < 16) {
    float acc = 0.f;
    const float4* wv = (const float4*)(x_proj_w + (size_t)(24 + tid) * 256);
    const float4* u4 = (const float4*)ul;
    for (int k = 0; k < 64; ++k) {
      float4 a = wv[k], c = u4[k];
      acc += c.x * a.x + c.y * a.y + c.z * a.z + c.w * a.w;
    }
    cm[tid] = acc;
  }
  __syncthreads();
  {
    const float* st = state + ((size_t)b * 256 + tid) * 16;
    float acc = 0.f;
#pragma unroll
    for (int n = 0; n < 16; ++n) acc += st[n] * cm[n];
    yv[tid] = (acc + ul[tid] * D_skip[tid]) * zs[tid];
  }
  __syncthreads();
  if (tid < 128) {
    float acc = 0.f;
    const float4* wv = (const float4*)(out_proj_w + (size_t)tid * 256);
    const float4* y4 = (const float4*)yv;
    for (int k = 0; k < 64; ++k) {
      float4 a = wv[k], c = y4[k];
      acc += c.x * a.x + c.y * a.y + c.z * a.z + c.w * a.w;
    }
    ov[tid] = acc;
  }
  __syncthreads();
  if (tid < 64) {
    float acc = fc1_b[tid];
    const float4* wv = (const float4*)(fc1_w + (size_t)tid * 128);
    const float4* o4 = (const float4*)ov;
    for (int k = 0; k < 32; ++k) {
      float4 a = wv[k], c = o4[k];
      acc += c.x * a.x + c.y * a.y + c.z * a.z + c.w * a.w;
    }
    hid[tid] = fmaxf(acc, 0.f);
  }
  __syncthreads();
  if (tid < N_CLS) {
    float acc = fc2_b[tid];
    const float* wv = fc2_w + (size_t)tid * 64;
    for (int k = 0; k < 64; ++k) acc += hid[k] * wv[k];
    out[b * N_CLS + tid] = acc;
  }
}

extern "C" void kernel_launch(void* const* d_in, const int* in_sizes, int n_in,
                              void* d_out, int out_size, void* d_ws, size_t ws_size,
                              hipStream_t stream) {
  (void)in_sizes; (void)n_in; (void)out_size; (void)ws_size;
  const float* x         = (const float*)d_in[0];
  const float* ip_w      = (const float*)d_in[1];
  const float* ip_b      = (const float*)d_in[2];
  const float* in_proj_w = (const float*)d_in[3];
  const float* conv_w    = (const float*)d_in[4];
  const float* conv_b    = (const float*)d_in[5];
  const float* x_proj_w  = (const float*)d_in[6];
  const float* dt_proj_w = (const float*)d_in[7];
  const float* dt_proj_b = (const float*)d_in[8];
  const float* A_log     = (const float*)d_in[9];
  const float* D_skip    = (const float*)d_in[10];
  const float* out_proj_w= (const float*)d_in[11];
  const float* fc1_w     = (const float*)d_in[12];
  const float* fc1_b     = (const float*)d_in[13];
  const float* fc2_w     = (const float*)d_in[14];
  const float* fc2_b     = (const float*)d_in[15];
  float* out = (float*)d_out;

  // no aliasing needed: total ~164 MB (u array eliminated by fusion)
  float* pk_delta = (float*)d_ws;                       // 16,384,000 f32
  float* pk_du    = pk_delta + (size_t)16384000;        // 16,384,000 f32
  float* pk_bm    = pk_du + (size_t)16384000;           //  1,024,000 f32
  float* state    = pk_bm + (size_t)1024000;            //    262,144 f32
  float* u_last   = state + (size_t)262144;             //     16,384 f32
  float* Qb       = u_last + (size_t)16384;             //  1,310,720 f32
  float* Pb       = Qb + (size_t)1310720;               //  1,310,720 f32
  char*  h_pk     = (char*)(Pb + (size_t)1310720);      // 16,777,216 B
  char*  w_pk     = h_pk + (size_t)64 * 64 * 4096;      //     65,536 B

  k0_prep<<<dim3(17, 64), 256, 0, stream>>>(x, ip_w, ip_b, in_proj_w, h_pk, w_pk);
  k1_fused<<<dim3(16, 64), 256, 0, stream>>>(h_pk, w_pk, conv_w, conv_b,
                                             x_proj_w, dt_proj_w, dt_proj_b,
                                             pk_delta, pk_du, pk_bm, u_last);
  k4_scan<<<dim3(16, 64, NCH), 256, 0, stream>>>(pk_delta, pk_du, pk_bm, A_log, Qb, Pb);
  k4b_combine<<<1024, 256, 0, stream>>>(Qb, Pb, state);
  k5_head<<<64, 256, 0, stream>>>(x, ip_w, ip_b, in_proj_w, x_proj_w, u_last, state,
                                  D_skip, out_proj_w, fc1_w, fc1_b, fc2_w, fc2_b, out);
}

// Round 15
// 218.158 us; speedup vs baseline: 1.2090x; 1.2090x over previous
//
#include <hip/hip_runtime.h>
#include <cstddef>

#define T_LEN 1000
#define B_SZ 64
#define C_IN_ 12
#define D_MODEL_ 128
#define D_INNER_ 256
#define D_STATE_ 16
#define DT_RANK_ 8
#define N_CLS 5
#define NCH 5       // scan time-chunks (200 steps each)

typedef __attribute__((ext_vector_type(8))) short bf16x8;
typedef __attribute__((ext_vector_type(8))) unsigned short u16x8;
typedef __attribute__((ext_vector_type(4))) float f32x4;

__device__ __forceinline__ float fast_exp2(float x) {
#if __has_builtin(__builtin_amdgcn_exp2f)
  return __builtin_amdgcn_exp2f(x);
#else
  float r; asm volatile("v_exp_f32 %0, %1" : "=v"(r) : "v"(x)); return r;
#endif
}
__device__ __forceinline__ float fast_log2(float x) {
#if __has_builtin(__builtin_amdgcn_logf)
  return __builtin_amdgcn_logf(x);
#else
  float r; asm volatile("v_log_f32 %0, %1" : "=v"(r) : "v"(x)); return r;
#endif
}
__device__ __forceinline__ float fast_rcp(float x) {
#if __has_builtin(__builtin_amdgcn_rcpf)
  return __builtin_amdgcn_rcpf(x);
#else
  float r; asm volatile("v_rcp_f32 %0, %1" : "=v"(r) : "v"(x)); return r;
#endif
}
__device__ __forceinline__ float silu_f(float x) {
  float den = 1.f + fast_exp2(-x * 1.4426950408889634f);
  return x * fast_rcp(den);
}
__device__ __forceinline__ float softplus_f(float x) {
  const float L = 1.4426950408889634f, iL = 0.6931471805599453f;
  float e = fast_exp2(-fabsf(x) * L);
  float l = fast_log2(1.f + e) * iL;
  return fmaxf(x, 0.f) + l;
}
__device__ __forceinline__ unsigned short f2bf(float f) {
  unsigned u = __builtin_bit_cast(unsigned, f);
  u = u + 0x7FFFu + ((u >> 16) & 1u);   // RNE
  return (unsigned short)(u >> 16);
}
__device__ __forceinline__ float bf2f(unsigned short h) {
  unsigned u = ((unsigned)h) << 16;
  return __builtin_bit_cast(float, u);
}

// K0: h = x@ip_w.T + ip_b (bf16, MFMA-frag-packed, zero-filled t>=1000) + W pack.
__global__ __launch_bounds__(256) void k0_prep(
    const float* __restrict__ x, const float* __restrict__ ip_w,
    const float* __restrict__ ip_b, const float* __restrict__ in_proj_w,
    char* __restrict__ h_pk, char* __restrict__ w_pk)
{
  __shared__ unsigned short pk_s[8192];
  __shared__ unsigned short pkw_s[32768];
  const int tid = threadIdx.x;

  if (blockIdx.x == 16) {                    // W-pack block
    if (blockIdx.y != 0) return;
    const int n = tid;
    for (int k = 0; k < D_MODEL_; ++k) {
      unsigned short v = f2bf(in_proj_w[(size_t)n * D_MODEL_ + k]);
      int off = ((n >> 4) * 4 + (k >> 5)) * 512 + ((k & 31) >> 3) * 128
              + (n & 15) * 8 + (k & 7);
      pkw_s[off] = v;
    }
    __syncthreads();
    const float4* s4 = (const float4*)pkw_s;
    float4* dst = (float4*)w_pk;
#pragma unroll
    for (int q = 0; q < 16; ++q) dst[tid * 16 + q] = s4[tid * 16 + q];
    return;
  }

  const int tile4 = blockIdx.x;
  const int b = blockIdx.y;
  const int rl = tid & 63;
  const int kc = (tid >> 6) * 32;
  const int t = tile4 * 64 + rl;

  float xr[C_IN_] = {0.f, 0.f, 0.f, 0.f, 0.f, 0.f, 0.f, 0.f, 0.f, 0.f, 0.f, 0.f};
  const bool valid = (t < T_LEN);
  if (valid) {
    const float4* xp = (const float4*)(x + ((size_t)b * T_LEN + t) * C_IN_);
    float4 v0 = xp[0], v1 = xp[1], v2 = xp[2];
    xr[0] = v0.x; xr[1] = v0.y; xr[2] = v0.z;  xr[3] = v0.w;
    xr[4] = v1.x; xr[5] = v1.y; xr[6] = v1.z;  xr[7] = v1.w;
    xr[8] = v2.x; xr[9] = v2.y; xr[10] = v2.z; xr[11] = v2.w;
  }
  for (int kk = 0; kk < 32; ++kk) {
    const int k = kc + kk;
    unsigned short v = 0;
    if (valid) {
      float acc = ip_b[k];
      const float* wr = ip_w + k * C_IN_;
#pragma unroll
      for (int c = 0; c < C_IN_; ++c) acc += xr[c] * wr[c];
      v = f2bf(acc);
    }
    int off = (rl >> 4) * 2048 + (k >> 5) * 512 + ((k & 31) >> 3) * 128
            + (rl & 15) * 8 + (k & 7);
    pk_s[off] = v;
  }
  __syncthreads();
  const float4* s4 = (const float4*)pk_s;
  float4* dst = (float4*)(h_pk + (size_t)(b * 64 + tile4 * 4) * 4096);
#pragma unroll
  for (int q = 0; q < 4; ++q) dst[tid * 4 + q] = s4[tid * 4 + q];
}

// K1 v9 (R12-proven): MFMA bf16 GEMM + halo + causal conv + fast-silu -> u.
__global__ __launch_bounds__(256) void k1_u(
    const char* __restrict__ h_pk, const char* __restrict__ w_pk,
    const float* __restrict__ conv_w, const float* __restrict__ conv_b,
    float* __restrict__ u_out)
{
  __shared__ float xm[67][260];

  const int tile = blockIdx.x;
  const int b    = blockIdx.y;
  const int t0   = tile * 64;
  const int tid  = threadIdx.x;
  const int w    = tid >> 6;
  const int l    = tid & 63;

  {
    const char* achunk = h_pk + (size_t)(b * 64 + tile * 4 + w) * 4096;
    bf16x8 a0 = *(const bf16x8*)(achunk + 0 * 1024 + l * 16);
    bf16x8 a1 = *(const bf16x8*)(achunk + 1 * 1024 + l * 16);
    bf16x8 a2 = *(const bf16x8*)(achunk + 2 * 1024 + l * 16);
    bf16x8 a3 = *(const bf16x8*)(achunk + 3 * 1024 + l * 16);

    const int row_l = w * 16 + (l >> 4) * 4;
#pragma unroll
    for (int nt = 0; nt < 16; ++nt) {
      const char* wb = w_pk + (size_t)nt * 4096 + l * 16;
      bf16x8 b0 = *(const bf16x8*)(wb + 0 * 1024);
      bf16x8 b1 = *(const bf16x8*)(wb + 1 * 1024);
      bf16x8 b2 = *(const bf16x8*)(wb + 2 * 1024);
      bf16x8 b3 = *(const bf16x8*)(wb + 3 * 1024);
      f32x4 acc = {0.f, 0.f, 0.f, 0.f};
      acc = __builtin_amdgcn_mfma_f32_16x16x32_bf16(a0, b0, acc, 0, 0, 0);
      acc = __builtin_amdgcn_mfma_f32_16x16x32_bf16(a1, b1, acc, 0, 0, 0);
      acc = __builtin_amdgcn_mfma_f32_16x16x32_bf16(a2, b2, acc, 0, 0, 0);
      acc = __builtin_amdgcn_mfma_f32_16x16x32_bf16(a3, b3, acc, 0, 0, 0);
      const int col = nt * 16 + (l & 15);
#pragma unroll
      for (int r = 0; r < 4; ++r)
        xm[3 + row_l + r][col] = acc[r];
    }
  }

  {
    const int n = tid;
    float hac[3] = {0.f, 0.f, 0.f};
    if (tile > 0) {
      const char* wrow = w_pk + (size_t)(n >> 4) * 4096 + (n & 15) * 16;
#pragma unroll
      for (int kt = 0; kt < 4; ++kt)
#pragma unroll
        for (int lg = 0; lg < 4; ++lg) {
          u16x8 wv = *(const u16x8*)(wrow + kt * 1024 + lg * 256);
#pragma unroll
          for (int r = 0; r < 3; ++r) {
            const int t = t0 - 3 + r;
            const char* hc = h_pk + (size_t)(b * 64 + (t >> 4)) * 4096;
            u16x8 hv = *(const u16x8*)(hc + kt * 1024 + lg * 256 + (t & 15) * 16);
#pragma unroll
            for (int j = 0; j < 8; ++j) hac[r] += bf2f(hv[j]) * bf2f(wv[j]);
          }
        }
    }
#pragma unroll
    for (int r = 0; r < 3; ++r) xm[r][n] = hac[r];
  }
  __syncthreads();

  {
    const int n = tid;
    const float4 cw = *(const float4*)&conv_w[n * 4];
    const float  cb = conv_b[n];
    float x0 = xm[0][n], x1 = xm[1][n], x2 = xm[2][n];
    for (int i = 0; i < 64; ++i) {
      const int t = t0 + i;
      float x3 = xm[3 + i][n];
      if (t < T_LEN) {
        float s = cb + x0 * cw.x + x1 * cw.y + x2 * cw.z + x3 * cw.w;
        u_out[(((size_t)b * T_LEN + t) << 8) + n] = silu_f(s);
      }
      x0 = x1; x1 = x2; x2 = x3;
    }
  }
}

// K3 v10: phase1 dbc = u @ xp[0:24].T; phase2 thread-per-d emits delta/du
// TRANSPOSED [b][d][1000] (per-thread contiguous rows; scatter stores are
// L2-absorbed since consecutive g fill the same 64B line); bm stays packed
// [b][t4][n][4]; u_last stashed.
__global__ __launch_bounds__(256) void k3_delta(
    const float* __restrict__ u, const float* __restrict__ x_proj_w,
    const float* __restrict__ dt_proj_w, const float* __restrict__ dt_proj_b,
    float* __restrict__ delta_T, float* __restrict__ du_T,
    float* __restrict__ pk_bm, float* __restrict__ u_last)
{
  __shared__ float4 xp4[24][65];
  __shared__ float dt_s[64][9];
  __shared__ float bm_s[64][17];

  const int row0 = blockIdx.x * 64;
  const int tid = threadIdx.x;

  for (int f = tid; f < 24 * 64; f += 256) {
    int c = f >> 6, k4 = f & 63;
    xp4[c][k4] = *(const float4*)&x_proj_w[(size_t)c * 256 + k4 * 4];
  }
  const float4 w0 = *(const float4*)&dt_proj_w[(size_t)tid * 8];
  const float4 w1 = *(const float4*)&dt_proj_w[(size_t)tid * 8 + 4];
  const float bias = dt_proj_b[tid];
  __syncthreads();

  // phase 1
  {
    const int r2 = tid >> 3, cg = tid & 7;
    const int ra = 2 * r2;
    const float4* ua4 = (const float4*)(u + (size_t)(row0 + ra) * 256);
    const float4* ub4 = (const float4*)(u + (size_t)(row0 + ra + 1) * 256);
    float a0 = 0.f, a1 = 0.f, a2 = 0.f, b0 = 0.f, b1 = 0.f, b2 = 0.f;
    for (int k4 = 0; k4 < 64; ++k4) {
      float4 a = ua4[k4], bb = ub4[k4];
      float4 q0 = xp4[cg * 3 + 0][k4];
      float4 q1 = xp4[cg * 3 + 1][k4];
      float4 q2 = xp4[cg * 3 + 2][k4];
      a0 += a.x * q0.x + a.y * q0.y + a.z * q0.z + a.w * q0.w;
      a1 += a.x * q1.x + a.y * q1.y + a.z * q1.z + a.w * q1.w;
      a2 += a.x * q2.x + a.y * q2.y + a.z * q2.z + a.w * q2.w;
      b0 += bb.x * q0.x + bb.y * q0.y + bb.z * q0.z + bb.w * q0.w;
      b1 += bb.x * q1.x + bb.y * q1.y + bb.z * q1.z + bb.w * q1.w;
      b2 += bb.x * q2.x + bb.y * q2.y + bb.z * q2.z + bb.w * q2.w;
    }
    float va[2][3] = {{a0, a1, a2}, {b0, b1, b2}};
#pragma unroll
    for (int rr = 0; rr < 2; ++rr)
#pragma unroll
      for (int c = 0; c < 3; ++c) {
        int col = cg * 3 + c;
        int row = ra + rr;
        if (col < 8) dt_s[row][col] = va[rr][c];
        else bm_s[row][col - 8] = va[rr][c];
      }
  }
  __syncthreads();

  // phase 2: thread = d; 8 groups of 8 t (groups never straddle b: 1000%8==0)
  for (int g = 0; g < 8; ++g) {
    float dd[8], uu[8];
#pragma unroll
    for (int j = 0; j < 8; ++j) {
      int r = g * 8 + j;
      float pre = bias
        + dt_s[r][0] * w0.x + dt_s[r][1] * w0.y + dt_s[r][2] * w0.z + dt_s[r][3] * w0.w
        + dt_s[r][4] * w1.x + dt_s[r][5] * w1.y + dt_s[r][6] * w1.z + dt_s[r][7] * w1.w;
      float dlt = softplus_f(pre);
      size_t o = (size_t)(row0 + r) * 256 + tid;
      float uv = u[o];
      dd[j] = dlt;
      uu[j] = dlt * uv;
      int rowg = row0 + r;
      if ((rowg - (rowg / 1000) * 1000) == 999)
        u_last[(rowg / 1000) * 256 + tid] = uv;
    }
    int row = row0 + g * 8;
    int bb_ = row / 1000;
    int t   = row - bb_ * 1000;          // multiple of 8
    size_t rb = ((size_t)(bb_ * 256 + tid)) * 1000 + t;
    *(float4*)&delta_T[rb]     = make_float4(dd[0], dd[1], dd[2], dd[3]);
    *(float4*)&delta_T[rb + 4] = make_float4(dd[4], dd[5], dd[6], dd[7]);
    *(float4*)&du_T[rb]        = make_float4(uu[0], uu[1], uu[2], uu[3]);
    *(float4*)&du_T[rb + 4]    = make_float4(uu[4], uu[5], uu[6], uu[7]);
  }
  if (tid < 16) {
    for (int g = 0; g < 8; ++g) {
      float pb[8];
#pragma unroll
      for (int j = 0; j < 8; ++j) pb[j] = bm_s[g * 8 + j][tid];
      int row = row0 + g * 8;
      int bb_ = row / 1000;
      int t   = row - bb_ * 1000;
      size_t base = (((size_t)bb_ * 250 + (t >> 2)) * 16 + tid) * 4;
      *(float4*)&pk_bm[base]      = make_float4(pb[0], pb[1], pb[2], pb[3]);
      *(float4*)&pk_bm[base + 64] = make_float4(pb[4], pb[5], pb[6], pb[7]);
    }
  }
}

// K4 v13: transposed [b][d][1000] operands -> FULLY-UNROLLED 50-iter loop with
// compile-time immediate offsets (zero address VALU, statically scheduled
// loads); bm chunk staged once in 12.8KB LDS (coalesced in, 2-way-free b128 out).
__global__ __launch_bounds__(256) void k4_scan(
    const float* __restrict__ delta_T, const float* __restrict__ du_T,
    const float* __restrict__ pk_bm, const float* __restrict__ A_log,
    float* __restrict__ Qb, float* __restrict__ Pb)
{
  __shared__ float bs[50][16][4];   // [t4_local][n][j], 12.8 KB

  const int d0 = blockIdx.x * 16;
  const int b  = blockIdx.y;
  const int c  = blockIdx.z;
  const int tid = threadIdx.x;
  const int dl = tid >> 4;
  const int n  = tid & 15;
  const int d  = d0 + dl;

  // stage bm chunk (800 float4s, coalesced)
  {
    const float4* src = (const float4*)(pk_bm + ((size_t)b * 250 + (size_t)c * 50) * 64);
    float4* dst = (float4*)bs;
    for (int f = tid; f < 800; f += 256) dst[f] = src[f];
  }
  const float A2 = -expf(A_log[(size_t)d * 16 + n]) * 1.4426950408889634f;
  const float* dp = delta_T + ((size_t)(b * 256 + d)) * 1000 + c * 200;
  const float* xp = du_T    + ((size_t)(b * 256 + d)) * 1000 + c * 200;
  __syncthreads();

  float s = 0.f, sum = 0.f;
#pragma unroll
  for (int i = 0; i < 50; ++i) {
    float4 dv = *(const float4*)(dp + 4 * i);   // offset 16i B: immediate
    float4 xv = *(const float4*)(xp + 4 * i);
    float4 bv = *(const float4*)&bs[i][n][0];   // LDS immediate offset
    sum += (dv.x + dv.y) + (dv.z + dv.w);
    s = fast_exp2(dv.x * A2) * s + xv.x * bv.x;
    s = fast_exp2(dv.y * A2) * s + xv.y * bv.y;
    s = fast_exp2(dv.z * A2) * s + xv.z * bv.z;
    s = fast_exp2(dv.w * A2) * s + xv.w * bv.w;
  }

  const size_t o = (size_t)c * 262144 + (size_t)b * 4096 + (size_t)d0 * 16 + tid;
  Qb[o] = s;
  Pb[o] = fast_exp2(A2 * sum);
}

// K4b: fold the NCH affine transitions -> final state.
__global__ __launch_bounds__(256) void k4b_combine(
    const float* __restrict__ Qb, const float* __restrict__ Pb,
    float* __restrict__ state_out)
{
  const size_t g = (size_t)blockIdx.x * 256 + threadIdx.x;   // 1024 blocks
  float s = Qb[g];
#pragma unroll
  for (int c = 1; c < NCH; ++c)
    s = Qb[(size_t)c * 262144 + g] + Pb[(size_t)c * 262144 + g] * s;
  state_out[g] = s;
}

// K5: per-batch head.
__global__ __launch_bounds__(256) void k5_head(
    const float* __restrict__ x, const float* __restrict__ ip_w,
    const float* __restrict__ ip_b, const float* __restrict__ in_proj_w,
    const float* __restrict__ x_proj_w, const float* __restrict__ u_last,
    const float* __restrict__ state, const float* __restrict__ D_skip,
    const float* __restrict__ out_proj_w, const float* __restrict__ fc1_w,
    const float* __restrict__ fc1_b, const float* __restrict__ fc2_w,
    const float* __restrict__ fc2_b, float* __restrict__ out)
{
  const int b = blockIdx.x, tid = threadIdx.x;
  __shared__ float hl[128], ul[256], zs[256], cm[16], yv[256], ov[128], hid[64];
  if (tid < 128) {
    float acc = ip_b[tid];
    const float* xr = x + ((size_t)b * T_LEN + (T_LEN - 1)) * C_IN_;
#pragma unroll
    for (int c = 0; c < C_IN_; ++c) acc += xr[c] * ip_w[tid * C_IN_ + c];
    hl[tid] = acc;
  }
  ul[tid] = u_last[b * 256 + tid];
  __syncthreads();
  {
    float acc = 0.f;
    const float4* wv = (const float4*)(in_proj_w + (size_t)(256 + tid) * 128);
    const float4* h4 = (const float4*)hl;
    for (int k = 0; k < 32; ++k) {
      float4 a = wv[k], c = h4[k];
      acc += c.x * a.x + c.y * a.y + c.z * a.z + c.w * a.w;
    }
    zs[tid] = silu_f(acc);
  }
  if (tid < 16) {
    float acc = 0.f;
    const float4* wv = (const float4*)(x_proj_w + (size_t)(24 + tid) * 256);
    const float4* u4 = (const float4*)ul;
    for (int k = 0; k < 64; ++k) {
      float4 a = wv[k], c = u4[k];
      acc += c.x * a.x + c.y * a.y + c.z * a.z + c.w * a.w;
    }
    cm[tid] = acc;
  }
  __syncthreads();
  {
    const float* st = state + ((size_t)b * 256 + tid) * 16;
    float acc = 0.f;
#pragma unroll
    for (int n = 0; n < 16; ++n) acc += st[n] * cm[n];
    yv[tid] = (acc + ul[tid] * D_skip[tid]) * zs[tid];
  }
  __syncthreads();
  if (tid < 128) {
    float acc = 0.f;
    const float4* wv = (const float4*)(out_proj_w + (size_t)tid * 256);
    const float4* y4 = (const float4*)yv;
    for (int k = 0; k < 64; ++k) {
      float4 a = wv[k], c = y4[k];
      acc += c.x * a.x + c.y * a.y + c.z * a.z + c.w * a.w;
    }
    ov[tid] = acc;
  }
  __syncthreads();
  if (tid < 64) {
    float acc = fc1_b[tid];
    const float4* wv = (const float4*)(fc1_w + (size_t)tid * 128);
    const float4* o4 = (const float4*)ov;
    for (int k = 0; k < 32; ++k) {
      float4 a = wv[k], c = o4[k];
      acc += c.x * a.x + c.y * a.y + c.z * a.z + c.w * a.w;
    }
    hid[tid] = fmaxf(acc, 0.f);
  }
  __syncthreads();
  if (tid < N_CLS) {
    float acc = fc2_b[tid];
    const float* wv = fc2_w + (size_t)tid * 64;
    for (int k = 0; k < 64; ++k) acc += hid[k] * wv[k];
    out[b * N_CLS + tid] = acc;
  }
}

extern "C" void kernel_launch(void* const* d_in, const int* in_sizes, int n_in,
                              void* d_out, int out_size, void* d_ws, size_t ws_size,
                              hipStream_t stream) {
  (void)in_sizes; (void)n_in; (void)out_size; (void)ws_size;
  const float* x         = (const float*)d_in[0];
  const float* ip_w      = (const float*)d_in[1];
  const float* ip_b      = (const float*)d_in[2];
  const float* in_proj_w = (const float*)d_in[3];
  const float* conv_w    = (const float*)d_in[4];
  const float* conv_b    = (const float*)d_in[5];
  const float* x_proj_w  = (const float*)d_in[6];
  const float* dt_proj_w = (const float*)d_in[7];
  const float* dt_proj_b = (const float*)d_in[8];
  const float* A_log     = (const float*)d_in[9];
  const float* D_skip    = (const float*)d_in[10];
  const float* out_proj_w= (const float*)d_in[11];
  const float* fc1_w     = (const float*)d_in[12];
  const float* fc1_b     = (const float*)d_in[13];
  const float* fc2_w     = (const float*)d_in[14];
  const float* fc2_b     = (const float*)d_in[15];
  float* out = (float*)d_out;

  float* u       = (float*)d_ws;                 // 16,384,000 f32 (65.5 MB)
  float* delta_T = u + (size_t)16384000;         // 16,384,000 f32 [b][256][1000]
  float* du_T    = delta_T + (size_t)16384000;   // 16,384,000 f32 [b][256][1000]
  float* pk_bm   = du_T + (size_t)16384000;      //  1,024,000 f32 [b][250][16][4]
  float* state   = pk_bm + (size_t)1024000;      //    262,144 f32
  float* u_last  = state + (size_t)262144;       //     16,384 f32 (201.8 MB total, proven)
  // aliases into regions dead at their use time (proven R12 pattern):
  char* h_pk = (char*)delta_T;                   // k0..k1 (delta_T written later by k3)
  char* w_pk = h_pk + (size_t)64 * 64 * 4096;
  float* Qb  = u;                                // k4..k4b (u dead after k3)
  float* Pb  = u + (size_t)2000000;

  k0_prep<<<dim3(17, 64), 256, 0, stream>>>(x, ip_w, ip_b, in_proj_w, h_pk, w_pk);
  k1_u<<<dim3(16, 64), 256, 0, stream>>>(h_pk, w_pk, conv_w, conv_b, u);
  k3_delta<<<1000, 256, 0, stream>>>(u, x_proj_w, dt_proj_w, dt_proj_b,
                                     delta_T, du_T, pk_bm, u_last);
  k4_scan<<<dim3(16, 64, NCH), 256, 0, stream>>>(delta_T, du_T, pk_bm, A_log, Qb, Pb);
  k4b_combine<<<1024, 256, 0, stream>>>(Qb, Pb, state);
  k5_head<<<64, 256, 0, stream>>>(x, ip_w, ip_b, in_proj_w, x_proj_w, u_last, state,
                                  D_skip, out_proj_w, fc1_w, fc1_b, fc2_w, fc2_b, out);
}

// Round 16
// 209.695 us; speedup vs baseline: 1.2578x; 1.0404x over previous
//
#include <hip/hip_runtime.h>
#include <cstddef>

#define T_LEN 1000
#define B_SZ 64
#define C_IN_ 12
#define D_MODEL_ 128
#define D_INNER_ 256
#define D_STATE_ 16
#define DT_RANK_ 8
#define N_CLS 5
#define NCH 10      // scan time-chunks (100 steps each)
#define CT4 25      // float4 groups per chunk

typedef __attribute__((ext_vector_type(8))) short bf16x8;
typedef __attribute__((ext_vector_type(8))) unsigned short u16x8;
typedef __attribute__((ext_vector_type(4))) float f32x4;

__device__ __forceinline__ float fast_exp2(float x) {
#if __has_builtin(__builtin_amdgcn_exp2f)
  return __builtin_amdgcn_exp2f(x);
#else
  float r; asm volatile("v_exp_f32 %0, %1" : "=v"(r) : "v"(x)); return r;
#endif
}
__device__ __forceinline__ float fast_log2(float x) {
#if __has_builtin(__builtin_amdgcn_logf)
  return __builtin_amdgcn_logf(x);
#else
  float r; asm volatile("v_log_f32 %0, %1" : "=v"(r) : "v"(x)); return r;
#endif
}
__device__ __forceinline__ float fast_rcp(float x) {
#if __has_builtin(__builtin_amdgcn_rcpf)
  return __builtin_amdgcn_rcpf(x);
#else
  float r; asm volatile("v_rcp_f32 %0, %1" : "=v"(r) : "v"(x)); return r;
#endif
}
__device__ __forceinline__ float silu_f(float x) {
  float den = 1.f + fast_exp2(-x * 1.4426950408889634f);
  return x * fast_rcp(den);
}
__device__ __forceinline__ float softplus_f(float x) {
  const float L = 1.4426950408889634f, iL = 0.6931471805599453f;
  float e = fast_exp2(-fabsf(x) * L);
  float l = fast_log2(1.f + e) * iL;
  return fmaxf(x, 0.f) + l;
}
__device__ __forceinline__ unsigned short f2bf(float f) {
  unsigned u = __builtin_bit_cast(unsigned, f);
  u = u + 0x7FFFu + ((u >> 16) & 1u);   // RNE
  return (unsigned short)(u >> 16);
}
__device__ __forceinline__ float bf2f(unsigned short h) {
  unsigned u = ((unsigned)h) << 16;
  return __builtin_bit_cast(float, u);
}

// K0: h = x@ip_w.T + ip_b (bf16, MFMA-frag-packed, zero-filled t>=1000) + W pack.
__global__ __launch_bounds__(256) void k0_prep(
    const float* __restrict__ x, const float* __restrict__ ip_w,
    const float* __restrict__ ip_b, const float* __restrict__ in_proj_w,
    char* __restrict__ h_pk, char* __restrict__ w_pk)
{
  __shared__ unsigned short pk_s[8192];
  __shared__ unsigned short pkw_s[32768];
  const int tid = threadIdx.x;

  if (blockIdx.x == 16) {                    // W-pack block
    if (blockIdx.y != 0) return;
    const int n = tid;
    for (int k = 0; k < D_MODEL_; ++k) {
      unsigned short v = f2bf(in_proj_w[(size_t)n * D_MODEL_ + k]);
      int off = ((n >> 4) * 4 + (k >> 5)) * 512 + ((k & 31) >> 3) * 128
              + (n & 15) * 8 + (k & 7);
      pkw_s[off] = v;
    }
    __syncthreads();
    const float4* s4 = (const float4*)pkw_s;
    float4* dst = (float4*)w_pk;
#pragma unroll
    for (int q = 0; q < 16; ++q) dst[tid * 16 + q] = s4[tid * 16 + q];
    return;
  }

  const int tile4 = blockIdx.x;
  const int b = blockIdx.y;
  const int rl = tid & 63;
  const int kc = (tid >> 6) * 32;
  const int t = tile4 * 64 + rl;

  float xr[C_IN_] = {0.f, 0.f, 0.f, 0.f, 0.f, 0.f, 0.f, 0.f, 0.f, 0.f, 0.f, 0.f};
  const bool valid = (t < T_LEN);
  if (valid) {
    const float4* xp = (const float4*)(x + ((size_t)b * T_LEN + t) * C_IN_);
    float4 v0 = xp[0], v1 = xp[1], v2 = xp[2];
    xr[0] = v0.x; xr[1] = v0.y; xr[2] = v0.z;  xr[3] = v0.w;
    xr[4] = v1.x; xr[5] = v1.y; xr[6] = v1.z;  xr[7] = v1.w;
    xr[8] = v2.x; xr[9] = v2.y; xr[10] = v2.z; xr[11] = v2.w;
  }
  for (int kk = 0; kk < 32; ++kk) {
    const int k = kc + kk;
    unsigned short v = 0;
    if (valid) {
      float acc = ip_b[k];
      const float* wr = ip_w + k * C_IN_;
#pragma unroll
      for (int c = 0; c < C_IN_; ++c) acc += xr[c] * wr[c];
      v = f2bf(acc);
    }
    int off = (rl >> 4) * 2048 + (k >> 5) * 512 + ((k & 31) >> 3) * 128
            + (rl & 15) * 8 + (k & 7);
    pk_s[off] = v;
  }
  __syncthreads();
  const float4* s4 = (const float4*)pk_s;
  float4* dst = (float4*)(h_pk + (size_t)(b * 64 + tile4 * 4) * 4096);
#pragma unroll
  for (int q = 0; q < 4; ++q) dst[tid * 4 + q] = s4[tid * 4 + q];
}

// K1 v9 (R12-proven): MFMA bf16 GEMM + halo + causal conv + fast-silu -> u.
__global__ __launch_bounds__(256) void k1_u(
    const char* __restrict__ h_pk, const char* __restrict__ w_pk,
    const float* __restrict__ conv_w, const float* __restrict__ conv_b,
    float* __restrict__ u_out)
{
  __shared__ float xm[67][260];

  const int tile = blockIdx.x;
  const int b    = blockIdx.y;
  const int t0   = tile * 64;
  const int tid  = threadIdx.x;
  const int w    = tid >> 6;
  const int l    = tid & 63;

  {
    const char* achunk = h_pk + (size_t)(b * 64 + tile * 4 + w) * 4096;
    bf16x8 a0 = *(const bf16x8*)(achunk + 0 * 1024 + l * 16);
    bf16x8 a1 = *(const bf16x8*)(achunk + 1 * 1024 + l * 16);
    bf16x8 a2 = *(const bf16x8*)(achunk + 2 * 1024 + l * 16);
    bf16x8 a3 = *(const bf16x8*)(achunk + 3 * 1024 + l * 16);

    const int row_l = w * 16 + (l >> 4) * 4;
#pragma unroll
    for (int nt = 0; nt < 16; ++nt) {
      const char* wb = w_pk + (size_t)nt * 4096 + l * 16;
      bf16x8 b0 = *(const bf16x8*)(wb + 0 * 1024);
      bf16x8 b1 = *(const bf16x8*)(wb + 1 * 1024);
      bf16x8 b2 = *(const bf16x8*)(wb + 2 * 1024);
      bf16x8 b3 = *(const bf16x8*)(wb + 3 * 1024);
      f32x4 acc = {0.f, 0.f, 0.f, 0.f};
      acc = __builtin_amdgcn_mfma_f32_16x16x32_bf16(a0, b0, acc, 0, 0, 0);
      acc = __builtin_amdgcn_mfma_f32_16x16x32_bf16(a1, b1, acc, 0, 0, 0);
      acc = __builtin_amdgcn_mfma_f32_16x16x32_bf16(a2, b2, acc, 0, 0, 0);
      acc = __builtin_amdgcn_mfma_f32_16x16x32_bf16(a3, b3, acc, 0, 0, 0);
      const int col = nt * 16 + (l & 15);
#pragma unroll
      for (int r = 0; r < 4; ++r)
        xm[3 + row_l + r][col] = acc[r];
    }
  }

  {
    const int n = tid;
    float hac[3] = {0.f, 0.f, 0.f};
    if (tile > 0) {
      const char* wrow = w_pk + (size_t)(n >> 4) * 4096 + (n & 15) * 16;
#pragma unroll
      for (int kt = 0; kt < 4; ++kt)
#pragma unroll
        for (int lg = 0; lg < 4; ++lg) {
          u16x8 wv = *(const u16x8*)(wrow + kt * 1024 + lg * 256);
#pragma unroll
          for (int r = 0; r < 3; ++r) {
            const int t = t0 - 3 + r;
            const char* hc = h_pk + (size_t)(b * 64 + (t >> 4)) * 4096;
            u16x8 hv = *(const u16x8*)(hc + kt * 1024 + lg * 256 + (t & 15) * 16);
#pragma unroll
            for (int j = 0; j < 8; ++j) hac[r] += bf2f(hv[j]) * bf2f(wv[j]);
          }
        }
    }
#pragma unroll
    for (int r = 0; r < 3; ++r) xm[r][n] = hac[r];
  }
  __syncthreads();

  {
    const int n = tid;
    const float4 cw = *(const float4*)&conv_w[n * 4];
    const float  cb = conv_b[n];
    float x0 = xm[0][n], x1 = xm[1][n], x2 = xm[2][n];
    for (int i = 0; i < 64; ++i) {
      const int t = t0 + i;
      float x3 = xm[3 + i][n];
      if (t < T_LEN) {
        float s = cb + x0 * cw.x + x1 * cw.y + x2 * cw.z + x3 * cw.w;
        u_out[(((size_t)b * T_LEN + t) << 8) + n] = silu_f(s);
      }
      x0 = x1; x1 = x2; x2 = x3;
    }
  }
}

// K3 v11: phase1 dbc = u @ xp[0:24].T; phase2 emits delta_T/du_T [b][d][1000]
// via LDS transpose bounce -> every wave store covers full 64B lines
// (fixes R14's 1.65x write amplification). LDS tile reuses xp4's storage.
__global__ __launch_bounds__(256) void k3_delta(
    const float* __restrict__ u, const float* __restrict__ x_proj_w,
    const float* __restrict__ dt_proj_w, const float* __restrict__ dt_proj_b,
    float* __restrict__ delta_T, float* __restrict__ du_T,
    float* __restrict__ pk_bm, float* __restrict__ u_last)
{
  __shared__ __align__(16) float smem[24 * 65 * 4];   // 24960 floats? no: 6240 floats (24.96KB)
  float4 (*xp4)[65] = reinterpret_cast<float4(*)[65]>(smem);   // phase 1 view
  float* tx = smem;                                            // phase 2 view (256*17=4352 fl)
  __shared__ float dt_s[64][9];
  __shared__ float bm_s[64][17];

  const int row0 = blockIdx.x * 64;
  const int tid = threadIdx.x;

  for (int f = tid; f < 24 * 64; f += 256) {
    int c = f >> 6, k4 = f & 63;
    xp4[c][k4] = *(const float4*)&x_proj_w[(size_t)c * 256 + k4 * 4];
  }
  const float4 w0 = *(const float4*)&dt_proj_w[(size_t)tid * 8];
  const float4 w1 = *(const float4*)&dt_proj_w[(size_t)tid * 8 + 4];
  const float bias = dt_proj_b[tid];
  __syncthreads();

  // phase 1
  {
    const int r2 = tid >> 3, cg = tid & 7;
    const int ra = 2 * r2;
    const float4* ua4 = (const float4*)(u + (size_t)(row0 + ra) * 256);
    const float4* ub4 = (const float4*)(u + (size_t)(row0 + ra + 1) * 256);
    float a0 = 0.f, a1 = 0.f, a2 = 0.f, b0 = 0.f, b1 = 0.f, b2 = 0.f;
    for (int k4 = 0; k4 < 64; ++k4) {
      float4 a = ua4[k4], bb = ub4[k4];
      float4 q0 = xp4[cg * 3 + 0][k4];
      float4 q1 = xp4[cg * 3 + 1][k4];
      float4 q2 = xp4[cg * 3 + 2][k4];
      a0 += a.x * q0.x + a.y * q0.y + a.z * q0.z + a.w * q0.w;
      a1 += a.x * q1.x + a.y * q1.y + a.z * q1.z + a.w * q1.w;
      a2 += a.x * q2.x + a.y * q2.y + a.z * q2.z + a.w * q2.w;
      b0 += bb.x * q0.x + bb.y * q0.y + bb.z * q0.z + bb.w * q0.w;
      b1 += bb.x * q1.x + bb.y * q1.y + bb.z * q1.z + bb.w * q1.w;
      b2 += bb.x * q2.x + bb.y * q2.y + bb.z * q2.z + bb.w * q2.w;
    }
    float va[2][3] = {{a0, a1, a2}, {b0, b1, b2}};
#pragma unroll
    for (int rr = 0; rr < 2; ++rr)
#pragma unroll
      for (int c = 0; c < 3; ++c) {
        int col = cg * 3 + c;
        int row = ra + rr;
        if (col < 8) dt_s[row][col] = va[rr][c];
        else bm_s[row][col - 8] = va[rr][c];
      }
  }
  __syncthreads();   // phase-1 xp4 reads done; tx may overwrite

  // phase 2: 4 chunks of 16 t; LDS transpose -> full-line coalesced stores
  for (int c16 = 0; c16 < 4; ++c16) {
    float dd[16], uu[16];
#pragma unroll
    for (int j = 0; j < 16; ++j) {
      int r = c16 * 16 + j;
      float pre = bias
        + dt_s[r][0] * w0.x + dt_s[r][1] * w0.y + dt_s[r][2] * w0.z + dt_s[r][3] * w0.w
        + dt_s[r][4] * w1.x + dt_s[r][5] * w1.y + dt_s[r][6] * w1.z + dt_s[r][7] * w1.w;
      float dlt = softplus_f(pre);
      size_t o = (size_t)(row0 + r) * 256 + tid;
      float uv = u[o];
      dd[j] = dlt;
      uu[j] = dlt * uv;
      int rowg = row0 + r;
      if ((rowg - (rowg / 1000) * 1000) == 999)
        u_last[(rowg / 1000) * 256 + tid] = uv;
    }
    // delta
#pragma unroll
    for (int j = 0; j < 16; ++j) tx[tid * 17 + j] = dd[j];
    __syncthreads();
#pragma unroll
    for (int q = 0; q < 4; ++q) {
      int d_ = (tid >> 2) + 64 * q;
      int t4 = (tid & 3) * 4;
      float4 v = make_float4(tx[d_ * 17 + t4], tx[d_ * 17 + t4 + 1],
                             tx[d_ * 17 + t4 + 2], tx[d_ * 17 + t4 + 3]);
      int rowg = row0 + c16 * 16 + t4;        // float4 never straddles b (1000%4==0)
      int bb = rowg / 1000;
      int t = rowg - bb * 1000;
      *(float4*)&delta_T[((size_t)(bb * 256 + d_)) * 1000 + t] = v;
    }
    __syncthreads();
    // du
#pragma unroll
    for (int j = 0; j < 16; ++j) tx[tid * 17 + j] = uu[j];
    __syncthreads();
#pragma unroll
    for (int q = 0; q < 4; ++q) {
      int d_ = (tid >> 2) + 64 * q;
      int t4 = (tid & 3) * 4;
      float4 v = make_float4(tx[d_ * 17 + t4], tx[d_ * 17 + t4 + 1],
                             tx[d_ * 17 + t4 + 2], tx[d_ * 17 + t4 + 3]);
      int rowg = row0 + c16 * 16 + t4;
      int bb = rowg / 1000;
      int t = rowg - bb * 1000;
      *(float4*)&du_T[((size_t)(bb * 256 + d_)) * 1000 + t] = v;
    }
    __syncthreads();
  }
  // bm pack (4 MB total; amplification negligible)
  if (tid < 16) {
    for (int g = 0; g < 8; ++g) {
      float pb[8];
#pragma unroll
      for (int j = 0; j < 8; ++j) pb[j] = bm_s[g * 8 + j][tid];
      int row = row0 + g * 8;
      int bb_ = row / 1000;
      int t   = row - bb_ * 1000;
      size_t base = (((size_t)bb_ * 250 + (t >> 2)) * 16 + tid) * 4;
      *(float4*)&pk_bm[base]      = make_float4(pb[0], pb[1], pb[2], pb[3]);
      *(float4*)&pk_bm[base + 64] = make_float4(pb[4], pb[5], pb[6], pb[7]);
    }
  }
}

// K4 v14: NCH=10 (100-step chunks, 2x blocks of R14 -> 8 resident/CU), same
// fully-unrolled immediate-offset loop; bm chunk staged in 6.4KB LDS.
__global__ __launch_bounds__(256) void k4_scan(
    const float* __restrict__ delta_T, const float* __restrict__ du_T,
    const float* __restrict__ pk_bm, const float* __restrict__ A_log,
    float* __restrict__ Qb, float* __restrict__ Pb)
{
  __shared__ float bs[CT4][16][4];   // [t4_local][n][j], 6.4 KB

  const int d0 = blockIdx.x * 16;
  const int b  = blockIdx.y;
  const int c  = blockIdx.z;
  const int tid = threadIdx.x;
  const int dl = tid >> 4;
  const int n  = tid & 15;
  const int d  = d0 + dl;

  {
    const float4* src = (const float4*)(pk_bm + ((size_t)b * 250 + (size_t)c * CT4) * 64);
    float4* dst = (float4*)bs;
    for (int f = tid; f < CT4 * 16; f += 256) dst[f] = src[f];
  }
  const float A2 = -expf(A_log[(size_t)d * 16 + n]) * 1.4426950408889634f;
  const float* dp = delta_T + ((size_t)(b * 256 + d)) * 1000 + c * 100;
  const float* xp = du_T    + ((size_t)(b * 256 + d)) * 1000 + c * 100;
  __syncthreads();

  float s = 0.f, sum = 0.f;
#pragma unroll
  for (int i = 0; i < CT4; ++i) {
    float4 dv = *(const float4*)(dp + 4 * i);   // 16i B: immediate offset
    float4 xv = *(const float4*)(xp + 4 * i);
    float4 bv = *(const float4*)&bs[i][n][0];
    sum += (dv.x + dv.y) + (dv.z + dv.w);
    s = fast_exp2(dv.x * A2) * s + xv.x * bv.x;
    s = fast_exp2(dv.y * A2) * s + xv.y * bv.y;
    s = fast_exp2(dv.z * A2) * s + xv.z * bv.z;
    s = fast_exp2(dv.w * A2) * s + xv.w * bv.w;
  }

  const size_t o = (size_t)c * 262144 + (size_t)b * 4096 + (size_t)d0 * 16 + tid;
  Qb[o] = s;
  Pb[o] = fast_exp2(A2 * sum);
}

// K4b: fold the NCH affine transitions -> final state.
__global__ __launch_bounds__(256) void k4b_combine(
    const float* __restrict__ Qb, const float* __restrict__ Pb,
    float* __restrict__ state_out)
{
  const size_t g = (size_t)blockIdx.x * 256 + threadIdx.x;   // 1024 blocks
  float s = Qb[g];
#pragma unroll
  for (int c = 1; c < NCH; ++c)
    s = Qb[(size_t)c * 262144 + g] + Pb[(size_t)c * 262144 + g] * s;
  state_out[g] = s;
}

// K5: per-batch head.
__global__ __launch_bounds__(256) void k5_head(
    const float* __restrict__ x, const float* __restrict__ ip_w,
    const float* __restrict__ ip_b, const float* __restrict__ in_proj_w,
    const float* __restrict__ x_proj_w, const float* __restrict__ u_last,
    const float* __restrict__ state, const float* __restrict__ D_skip,
    const float* __restrict__ out_proj_w, const float* __restrict__ fc1_w,
    const float* __restrict__ fc1_b, const float* __restrict__ fc2_w,
    const float* __restrict__ fc2_b, float* __restrict__ out)
{
  const int b = blockIdx.x, tid = threadIdx.x;
  __shared__ float hl[128], ul[256], zs[256], cm[16], yv[256], ov[128], hid[64];
  if (tid < 128) {
    float acc = ip_b[tid];
    const float* xr = x + ((size_t)b * T_LEN + (T_LEN - 1)) * C_IN_;
#pragma unroll
    for (int c = 0; c < C_IN_; ++c) acc += xr[c] * ip_w[tid * C_IN_ + c];
    hl[tid] = acc;
  }
  ul[tid] = u_last[b * 256 + tid];
  __syncthreads();
  {
    float acc = 0.f;
    const float4* wv = (const float4*)(in_proj_w + (size_t)(256 + tid) * 128);
    const float4* h4 = (const float4*)hl;
    for (int k = 0; k < 32; ++k) {
      float4 a = wv[k], c = h4[k];
      acc += c.x * a.x + c.y * a.y + c.z * a.z + c.w * a.w;
    }
    zs[tid] = silu_f(acc);
  }
  if (tid < 16) {
    float acc = 0.f;
    const float4* wv = (const float4*)(x_proj_w + (size_t)(24 + tid) * 256);
    const float4* u4 = (const float4*)ul;
    for (int k = 0; k < 64; ++k) {
      float4 a = wv[k], c = u4[k];
      acc += c.x * a.x + c.y * a.y + c.z * a.z + c.w * a.w;
    }
    cm[tid] = acc;
  }
  __syncthreads();
  {
    const float* st = state + ((size_t)b * 256 + tid) * 16;
    float acc = 0.f;
#pragma unroll
    for (int n = 0; n < 16; ++n) acc += st[n] * cm[n];
    yv[tid] = (acc + ul[tid] * D_skip[tid]) * zs[tid];
  }
  __syncthreads();
  if (tid < 128) {
    float acc = 0.f;
    const float4* wv = (const float4*)(out_proj_w + (size_t)tid * 256);
    const float4* y4 = (const float4*)yv;
    for (int k = 0; k < 64; ++k) {
      float4 a = wv[k], c = y4[k];
      acc += c.x * a.x + c.y * a.y + c.z * a.z + c.w * a.w;
    }
    ov[tid] = acc;
  }
  __syncthreads();
  if (tid < 64) {
    float acc = fc1_b[tid];
    const float4* wv = (const float4*)(fc1_w + (size_t)tid * 128);
    const float4* o4 = (const float4*)ov;
    for (int k = 0; k < 32; ++k) {
      float4 a = wv[k], c = o4[k];
      acc += c.x * a.x + c.y * a.y + c.z * a.z + c.w * a.w;
    }
    hid[tid] = fmaxf(acc, 0.f);
  }
  __syncthreads();
  if (tid < N_CLS) {
    float acc = fc2_b[tid];
    const float* wv = fc2_w + (size_t)tid * 64;
    for (int k = 0; k < 64; ++k) acc += hid[k] * wv[k];
    out[b * N_CLS + tid] = acc;
  }
}

extern "C" void kernel_launch(void* const* d_in, const int* in_sizes, int n_in,
                              void* d_out, int out_size, void* d_ws, size_t ws_size,
                              hipStream_t stream) {
  (void)in_sizes; (void)n_in; (void)out_size; (void)ws_size;
  const float* x         = (const float*)d_in[0];
  const float* ip_w      = (const float*)d_in[1];
  const float* ip_b      = (const float*)d_in[2];
  const float* in_proj_w = (const float*)d_in[3];
  const float* conv_w    = (const float*)d_in[4];
  const float* conv_b    = (const float*)d_in[5];
  const float* x_proj_w  = (const float*)d_in[6];
  const float* dt_proj_w = (const float*)d_in[7];
  const float* dt_proj_b = (const float*)d_in[8];
  const float* A_log     = (const float*)d_in[9];
  const float* D_skip    = (const float*)d_in[10];
  const float* out_proj_w= (const float*)d_in[11];
  const float* fc1_w     = (const float*)d_in[12];
  const float* fc1_b     = (const float*)d_in[13];
  const float* fc2_w     = (const float*)d_in[14];
  const float* fc2_b     = (const float*)d_in[15];
  float* out = (float*)d_out;

  float* u       = (float*)d_ws;                 // 16,384,000 f32 (65.5 MB)
  float* delta_T = u + (size_t)16384000;         // 16,384,000 f32 [b][256][1000]
  float* du_T    = delta_T + (size_t)16384000;   // 16,384,000 f32 [b][256][1000]
  float* pk_bm   = du_T + (size_t)16384000;      //  1,024,000 f32 [b][250][16][4]
  float* state   = pk_bm + (size_t)1024000;      //    262,144 f32
  float* u_last  = state + (size_t)262144;       //     16,384 f32 (201.8 MB, proven)
  // aliases into regions dead at their use time (proven pattern):
  char* h_pk = (char*)delta_T;                   // k0..k1 (delta_T written later by k3)
  char* w_pk = h_pk + (size_t)64 * 64 * 4096;
  float* Qb  = u;                                // k4..k4b (u dead after k3); 2.62M fl
  float* Pb  = u + (size_t)4000000;              // 2.62M fl

  k0_prep<<<dim3(17, 64), 256, 0, stream>>>(x, ip_w, ip_b, in_proj_w, h_pk, w_pk);
  k1_u<<<dim3(16, 64), 256, 0, stream>>>(h_pk, w_pk, conv_w, conv_b, u);
  k3_delta<<<1000, 256, 0, stream>>>(u, x_proj_w, dt_proj_w, dt_proj_b,
                                     delta_T, du_T, pk_bm, u_last);
  k4_scan<<<dim3(16, 64, NCH), 256, 0, stream>>>(delta_T, du_T, pk_bm, A_log, Qb, Pb);
  k4b_combine<<<1024, 256, 0, stream>>>(Qb, Pb, state);
  k5_head<<<64, 256, 0, stream>>>(x, ip_w, ip_b, in_proj_w, x_proj_w, u_last, state,
                                  D_skip, out_proj_w, fc1_w, fc1_b, fc2_w, fc2_b, out);
}

// Round 17
// 203.563 us; speedup vs baseline: 1.2957x; 1.0301x over previous
//
#include <hip/hip_runtime.h>
#include <cstddef>

#define T_LEN 1000
#define B_SZ 64
#define C_IN_ 12
#define D_MODEL_ 128
#define D_INNER_ 256
#define D_STATE_ 16
#define DT_RANK_ 8
#define N_CLS 5
#define NCH 10      // scan time-chunks (100 steps each)
#define CT4 25      // float4 groups per chunk

typedef __attribute__((ext_vector_type(8))) short bf16x8;
typedef __attribute__((ext_vector_type(8))) unsigned short u16x8;
typedef __attribute__((ext_vector_type(4))) float f32x4;

__device__ __forceinline__ float fast_exp2(float x) {
#if __has_builtin(__builtin_amdgcn_exp2f)
  return __builtin_amdgcn_exp2f(x);
#else
  float r; asm volatile("v_exp_f32 %0, %1" : "=v"(r) : "v"(x)); return r;
#endif
}
__device__ __forceinline__ float fast_log2(float x) {
#if __has_builtin(__builtin_amdgcn_logf)
  return __builtin_amdgcn_logf(x);
#else
  float r; asm volatile("v_log_f32 %0, %1" : "=v"(r) : "v"(x)); return r;
#endif
}
__device__ __forceinline__ float fast_rcp(float x) {
#if __has_builtin(__builtin_amdgcn_rcpf)
  return __builtin_amdgcn_rcpf(x);
#else
  float r; asm volatile("v_rcp_f32 %0, %1" : "=v"(r) : "v"(x)); return r;
#endif
}
__device__ __forceinline__ float silu_f(float x) {
  float den = 1.f + fast_exp2(-x * 1.4426950408889634f);
  return x * fast_rcp(den);
}
__device__ __forceinline__ float softplus_f(float x) {
  const float L = 1.4426950408889634f, iL = 0.6931471805599453f;
  float e = fast_exp2(-fabsf(x) * L);
  float l = fast_log2(1.f + e) * iL;
  return fmaxf(x, 0.f) + l;
}
__device__ __forceinline__ unsigned short f2bf(float f) {
  unsigned u = __builtin_bit_cast(unsigned, f);
  u = u + 0x7FFFu + ((u >> 16) & 1u);   // RNE
  return (unsigned short)(u >> 16);
}
__device__ __forceinline__ float bf2f(unsigned short h) {
  unsigned u = ((unsigned)h) << 16;
  return __builtin_bit_cast(float, u);
}

// K0: h = x@ip_w.T + ip_b (bf16, MFMA-frag-packed, zero-filled t>=1000) + W pack.
__global__ __launch_bounds__(256) void k0_prep(
    const float* __restrict__ x, const float* __restrict__ ip_w,
    const float* __restrict__ ip_b, const float* __restrict__ in_proj_w,
    char* __restrict__ h_pk, char* __restrict__ w_pk)
{
  __shared__ unsigned short pk_s[8192];
  __shared__ unsigned short pkw_s[32768];
  const int tid = threadIdx.x;

  if (blockIdx.x == 16) {                    // W-pack block
    if (blockIdx.y != 0) return;
    const int n = tid;
    for (int k = 0; k < D_MODEL_; ++k) {
      unsigned short v = f2bf(in_proj_w[(size_t)n * D_MODEL_ + k]);
      int off = ((n >> 4) * 4 + (k >> 5)) * 512 + ((k & 31) >> 3) * 128
              + (n & 15) * 8 + (k & 7);
      pkw_s[off] = v;
    }
    __syncthreads();
    const float4* s4 = (const float4*)pkw_s;
    float4* dst = (float4*)w_pk;
#pragma unroll
    for (int q = 0; q < 16; ++q) dst[tid * 16 + q] = s4[tid * 16 + q];
    return;
  }

  const int tile4 = blockIdx.x;
  const int b = blockIdx.y;
  const int rl = tid & 63;
  const int kc = (tid >> 6) * 32;
  const int t = tile4 * 64 + rl;

  float xr[C_IN_] = {0.f, 0.f, 0.f, 0.f, 0.f, 0.f, 0.f, 0.f, 0.f, 0.f, 0.f, 0.f};
  const bool valid = (t < T_LEN);
  if (valid) {
    const float4* xp = (const float4*)(x + ((size_t)b * T_LEN + t) * C_IN_);
    float4 v0 = xp[0], v1 = xp[1], v2 = xp[2];
    xr[0] = v0.x; xr[1] = v0.y; xr[2] = v0.z;  xr[3] = v0.w;
    xr[4] = v1.x; xr[5] = v1.y; xr[6] = v1.z;  xr[7] = v1.w;
    xr[8] = v2.x; xr[9] = v2.y; xr[10] = v2.z; xr[11] = v2.w;
  }
  for (int kk = 0; kk < 32; ++kk) {
    const int k = kc + kk;
    unsigned short v = 0;
    if (valid) {
      float acc = ip_b[k];
      const float* wr = ip_w + k * C_IN_;
#pragma unroll
      for (int c = 0; c < C_IN_; ++c) acc += xr[c] * wr[c];
      v = f2bf(acc);
    }
    int off = (rl >> 4) * 2048 + (k >> 5) * 512 + ((k & 31) >> 3) * 128
            + (rl & 15) * 8 + (k & 7);
    pk_s[off] = v;
  }
  __syncthreads();
  const float4* s4 = (const float4*)pk_s;
  float4* dst = (float4*)(h_pk + (size_t)(b * 64 + tile4 * 4) * 4096);
#pragma unroll
  for (int q = 0; q < 4; ++q) dst[tid * 4 + q] = s4[tid * 4 + q];
}

// K1 v10: MFMA bf16 GEMM; halo rows now ALSO via MFMA (prev 16-row chunk,
// keep rows 13..15) -- removes the ~1280-VALU-inst/thread vector-dot path.
__global__ __launch_bounds__(256) void k1_u(
    const char* __restrict__ h_pk, const char* __restrict__ w_pk,
    const float* __restrict__ conv_w, const float* __restrict__ conv_b,
    float* __restrict__ u_out)
{
  __shared__ float xm[67][260];

  const int tile = blockIdx.x;
  const int b    = blockIdx.y;
  const int t0   = tile * 64;
  const int tid  = threadIdx.x;
  const int w    = tid >> 6;
  const int l    = tid & 63;

  // --- main MFMA phase: rows t0..t0+63 ---
  {
    const char* achunk = h_pk + (size_t)(b * 64 + tile * 4 + w) * 4096;
    bf16x8 a0 = *(const bf16x8*)(achunk + 0 * 1024 + l * 16);
    bf16x8 a1 = *(const bf16x8*)(achunk + 1 * 1024 + l * 16);
    bf16x8 a2 = *(const bf16x8*)(achunk + 2 * 1024 + l * 16);
    bf16x8 a3 = *(const bf16x8*)(achunk + 3 * 1024 + l * 16);

    const int row_l = w * 16 + (l >> 4) * 4;
#pragma unroll
    for (int nt = 0; nt < 16; ++nt) {
      const char* wb = w_pk + (size_t)nt * 4096 + l * 16;
      bf16x8 b0 = *(const bf16x8*)(wb + 0 * 1024);
      bf16x8 b1 = *(const bf16x8*)(wb + 1 * 1024);
      bf16x8 b2 = *(const bf16x8*)(wb + 2 * 1024);
      bf16x8 b3 = *(const bf16x8*)(wb + 3 * 1024);
      f32x4 acc = {0.f, 0.f, 0.f, 0.f};
      acc = __builtin_amdgcn_mfma_f32_16x16x32_bf16(a0, b0, acc, 0, 0, 0);
      acc = __builtin_amdgcn_mfma_f32_16x16x32_bf16(a1, b1, acc, 0, 0, 0);
      acc = __builtin_amdgcn_mfma_f32_16x16x32_bf16(a2, b2, acc, 0, 0, 0);
      acc = __builtin_amdgcn_mfma_f32_16x16x32_bf16(a3, b3, acc, 0, 0, 0);
      const int col = nt * 16 + (l & 15);
#pragma unroll
      for (int r = 0; r < 4; ++r)
        xm[3 + row_l + r][col] = acc[r];
    }
  }

  // --- halo rows t0-3..t0-1 via MFMA on chunk (tile*4 - 1); D rows 13..15 ---
  if (tile > 0) {
    const char* hchunk = h_pk + (size_t)(b * 64 + tile * 4 - 1) * 4096;
    bf16x8 ha0 = *(const bf16x8*)(hchunk + 0 * 1024 + l * 16);
    bf16x8 ha1 = *(const bf16x8*)(hchunk + 1 * 1024 + l * 16);
    bf16x8 ha2 = *(const bf16x8*)(hchunk + 2 * 1024 + l * 16);
    bf16x8 ha3 = *(const bf16x8*)(hchunk + 3 * 1024 + l * 16);
#pragma unroll
    for (int q = 0; q < 4; ++q) {
      const int nt = w * 4 + q;              // 4 waves x 4 nt = all 16 n-tiles
      const char* wb = w_pk + (size_t)nt * 4096 + l * 16;
      bf16x8 b0 = *(const bf16x8*)(wb + 0 * 1024);
      bf16x8 b1 = *(const bf16x8*)(wb + 1 * 1024);
      bf16x8 b2 = *(const bf16x8*)(wb + 2 * 1024);
      bf16x8 b3 = *(const bf16x8*)(wb + 3 * 1024);
      f32x4 acc = {0.f, 0.f, 0.f, 0.f};
      acc = __builtin_amdgcn_mfma_f32_16x16x32_bf16(ha0, b0, acc, 0, 0, 0);
      acc = __builtin_amdgcn_mfma_f32_16x16x32_bf16(ha1, b1, acc, 0, 0, 0);
      acc = __builtin_amdgcn_mfma_f32_16x16x32_bf16(ha2, b2, acc, 0, 0, 0);
      acc = __builtin_amdgcn_mfma_f32_16x16x32_bf16(ha3, b3, acc, 0, 0, 0);
      if (l >= 48) {                         // rows 12+r; keep 13,14,15
        const int col = nt * 16 + (l & 15);
        xm[0][col] = acc[1];
        xm[1][col] = acc[2];
        xm[2][col] = acc[3];
      }
    }
  } else {
#pragma unroll
    for (int r = 0; r < 3; ++r) xm[r][tid] = 0.f;
  }
  __syncthreads();

  // --- conv + silu + store u ---
  {
    const int n = tid;
    const float4 cw = *(const float4*)&conv_w[n * 4];
    const float  cb = conv_b[n];
    float x0 = xm[0][n], x1 = xm[1][n], x2 = xm[2][n];
    for (int i = 0; i < 64; ++i) {
      const int t = t0 + i;
      float x3 = xm[3 + i][n];
      if (t < T_LEN) {
        float s = cb + x0 * cw.x + x1 * cw.y + x2 * cw.z + x3 * cw.w;
        u_out[(((size_t)b * T_LEN + t) << 8) + n] = silu_f(s);
      }
      x0 = x1; x1 = x2; x2 = x3;
    }
  }
}

// K3 v11 (R15-proven): phase1 dbc GEMM; phase2 LDS-transpose-bounced
// full-line stores of delta_T/du_T [b][d][1000]; bm packed; u_last stashed.
__global__ __launch_bounds__(256) void k3_delta(
    const float* __restrict__ u, const float* __restrict__ x_proj_w,
    const float* __restrict__ dt_proj_w, const float* __restrict__ dt_proj_b,
    float* __restrict__ delta_T, float* __restrict__ du_T,
    float* __restrict__ pk_bm, float* __restrict__ u_last)
{
  __shared__ __align__(16) float smem[24 * 65 * 4];
  float4 (*xp4)[65] = reinterpret_cast<float4(*)[65]>(smem);   // phase 1 view
  float* tx = smem;                                            // phase 2 view
  __shared__ float dt_s[64][9];
  __shared__ float bm_s[64][17];

  const int row0 = blockIdx.x * 64;
  const int tid = threadIdx.x;

  for (int f = tid; f < 24 * 64; f += 256) {
    int c = f >> 6, k4 = f & 63;
    xp4[c][k4] = *(const float4*)&x_proj_w[(size_t)c * 256 + k4 * 4];
  }
  const float4 w0 = *(const float4*)&dt_proj_w[(size_t)tid * 8];
  const float4 w1 = *(const float4*)&dt_proj_w[(size_t)tid * 8 + 4];
  const float bias = dt_proj_b[tid];
  __syncthreads();

  // phase 1
  {
    const int r2 = tid >> 3, cg = tid & 7;
    const int ra = 2 * r2;
    const float4* ua4 = (const float4*)(u + (size_t)(row0 + ra) * 256);
    const float4* ub4 = (const float4*)(u + (size_t)(row0 + ra + 1) * 256);
    float a0 = 0.f, a1 = 0.f, a2 = 0.f, b0 = 0.f, b1 = 0.f, b2 = 0.f;
    for (int k4 = 0; k4 < 64; ++k4) {
      float4 a = ua4[k4], bb = ub4[k4];
      float4 q0 = xp4[cg * 3 + 0][k4];
      float4 q1 = xp4[cg * 3 + 1][k4];
      float4 q2 = xp4[cg * 3 + 2][k4];
      a0 += a.x * q0.x + a.y * q0.y + a.z * q0.z + a.w * q0.w;
      a1 += a.x * q1.x + a.y * q1.y + a.z * q1.z + a.w * q1.w;
      a2 += a.x * q2.x + a.y * q2.y + a.z * q2.z + a.w * q2.w;
      b0 += bb.x * q0.x + bb.y * q0.y + bb.z * q0.z + bb.w * q0.w;
      b1 += bb.x * q1.x + bb.y * q1.y + bb.z * q1.z + bb.w * q1.w;
      b2 += bb.x * q2.x + bb.y * q2.y + bb.z * q2.z + bb.w * q2.w;
    }
    float va[2][3] = {{a0, a1, a2}, {b0, b1, b2}};
#pragma unroll
    for (int rr = 0; rr < 2; ++rr)
#pragma unroll
      for (int c = 0; c < 3; ++c) {
        int col = cg * 3 + c;
        int row = ra + rr;
        if (col < 8) dt_s[row][col] = va[rr][c];
        else bm_s[row][col - 8] = va[rr][c];
      }
  }
  __syncthreads();   // phase-1 xp4 reads done; tx may overwrite

  // phase 2: 4 chunks of 16 t; LDS transpose -> full-line coalesced stores
  for (int c16 = 0; c16 < 4; ++c16) {
    float dd[16], uu[16];
#pragma unroll
    for (int j = 0; j < 16; ++j) {
      int r = c16 * 16 + j;
      float pre = bias
        + dt_s[r][0] * w0.x + dt_s[r][1] * w0.y + dt_s[r][2] * w0.z + dt_s[r][3] * w0.w
        + dt_s[r][4] * w1.x + dt_s[r][5] * w1.y + dt_s[r][6] * w1.z + dt_s[r][7] * w1.w;
      float dlt = softplus_f(pre);
      size_t o = (size_t)(row0 + r) * 256 + tid;
      float uv = u[o];
      dd[j] = dlt;
      uu[j] = dlt * uv;
      int rowg = row0 + r;
      if ((rowg - (rowg / 1000) * 1000) == 999)
        u_last[(rowg / 1000) * 256 + tid] = uv;
    }
#pragma unroll
    for (int j = 0; j < 16; ++j) tx[tid * 17 + j] = dd[j];
    __syncthreads();
#pragma unroll
    for (int q = 0; q < 4; ++q) {
      int d_ = (tid >> 2) + 64 * q;
      int t4 = (tid & 3) * 4;
      float4 v = make_float4(tx[d_ * 17 + t4], tx[d_ * 17 + t4 + 1],
                             tx[d_ * 17 + t4 + 2], tx[d_ * 17 + t4 + 3]);
      int rowg = row0 + c16 * 16 + t4;
      int bb = rowg / 1000;
      int t = rowg - bb * 1000;
      *(float4*)&delta_T[((size_t)(bb * 256 + d_)) * 1000 + t] = v;
    }
    __syncthreads();
#pragma unroll
    for (int j = 0; j < 16; ++j) tx[tid * 17 + j] = uu[j];
    __syncthreads();
#pragma unroll
    for (int q = 0; q < 4; ++q) {
      int d_ = (tid >> 2) + 64 * q;
      int t4 = (tid & 3) * 4;
      float4 v = make_float4(tx[d_ * 17 + t4], tx[d_ * 17 + t4 + 1],
                             tx[d_ * 17 + t4 + 2], tx[d_ * 17 + t4 + 3]);
      int rowg = row0 + c16 * 16 + t4;
      int bb = rowg / 1000;
      int t = rowg - bb * 1000;
      *(float4*)&du_T[((size_t)(bb * 256 + d_)) * 1000 + t] = v;
    }
    __syncthreads();
  }
  if (tid < 16) {
    for (int g = 0; g < 8; ++g) {
      float pb[8];
#pragma unroll
      for (int j = 0; j < 8; ++j) pb[j] = bm_s[g * 8 + j][tid];
      int row = row0 + g * 8;
      int bb_ = row / 1000;
      int t   = row - bb_ * 1000;
      size_t base = (((size_t)bb_ * 250 + (t >> 2)) * 16 + tid) * 4;
      *(float4*)&pk_bm[base]      = make_float4(pb[0], pb[1], pb[2], pb[3]);
      *(float4*)&pk_bm[base + 64] = make_float4(pb[4], pb[5], pb[6], pb[7]);
    }
  }
}

// K4 v15: same immediate-offset fully-unrolled loop, but launch_bounds(256,4)
// frees up to 128 VGPRs so the compiler can hoist many iterations of loads
// (R16's 32-VGPR allocation forced load-wait-compute per iteration).
__global__ __launch_bounds__(256, 4) void k4_scan(
    const float* __restrict__ delta_T, const float* __restrict__ du_T,
    const float* __restrict__ pk_bm, const float* __restrict__ A_log,
    float* __restrict__ Qb, float* __restrict__ Pb)
{
  __shared__ float bs[CT4][16][4];   // [t4_local][n][j], 6.4 KB

  const int d0 = blockIdx.x * 16;
  const int b  = blockIdx.y;
  const int c  = blockIdx.z;
  const int tid = threadIdx.x;
  const int dl = tid >> 4;
  const int n  = tid & 15;
  const int d  = d0 + dl;

  {
    const float4* src = (const float4*)(pk_bm + ((size_t)b * 250 + (size_t)c * CT4) * 64);
    float4* dst = (float4*)bs;
    for (int f = tid; f < CT4 * 16; f += 256) dst[f] = src[f];
  }
  const float A2 = -expf(A_log[(size_t)d * 16 + n]) * 1.4426950408889634f;
  const float* dp = delta_T + ((size_t)(b * 256 + d)) * 1000 + c * 100;
  const float* xp = du_T    + ((size_t)(b * 256 + d)) * 1000 + c * 100;
  __syncthreads();

  float s = 0.f, sum = 0.f;
#pragma unroll
  for (int i = 0; i < CT4; ++i) {
    float4 dv = *(const float4*)(dp + 4 * i);   // 16i B: immediate offset
    float4 xv = *(const float4*)(xp + 4 * i);
    float4 bv = *(const float4*)&bs[i][n][0];
    sum += (dv.x + dv.y) + (dv.z + dv.w);
    s = fast_exp2(dv.x * A2) * s + xv.x * bv.x;
    s = fast_exp2(dv.y * A2) * s + xv.y * bv.y;
    s = fast_exp2(dv.z * A2) * s + xv.z * bv.z;
    s = fast_exp2(dv.w * A2) * s + xv.w * bv.w;
  }

  const size_t o = (size_t)c * 262144 + (size_t)b * 4096 + (size_t)d0 * 16 + tid;
  Qb[o] = s;
  Pb[o] = fast_exp2(A2 * sum);
}

// K4b: fold the NCH affine transitions -> final state.
__global__ __launch_bounds__(256) void k4b_combine(
    const float* __restrict__ Qb, const float* __restrict__ Pb,
    float* __restrict__ state_out)
{
  const size_t g = (size_t)blockIdx.x * 256 + threadIdx.x;   // 1024 blocks
  float s = Qb[g];
#pragma unroll
  for (int c = 1; c < NCH; ++c)
    s = Qb[(size_t)c * 262144 + g] + Pb[(size_t)c * 262144 + g] * s;
  state_out[g] = s;
}

// K5: per-batch head.
__global__ __launch_bounds__(256) void k5_head(
    const float* __restrict__ x, const float* __restrict__ ip_w,
    const float* __restrict__ ip_b, const float* __restrict__ in_proj_w,
    const float* __restrict__ x_proj_w, const float* __restrict__ u_last,
    const float* __restrict__ state, const float* __restrict__ D_skip,
    const float* __restrict__ out_proj_w, const float* __restrict__ fc1_w,
    const float* __restrict__ fc1_b, const float* __restrict__ fc2_w,
    const float* __restrict__ fc2_b, float* __restrict__ out)
{
  const int b = blockIdx.x, tid = threadIdx.x;
  __shared__ float hl[128], ul[256], zs[256], cm[16], yv[256], ov[128], hid[64];
  if (tid < 128) {
    float acc = ip_b[tid];
    const float* xr = x + ((size_t)b * T_LEN + (T_LEN - 1)) * C_IN_;
#pragma unroll
    for (int c = 0; c < C_IN_; ++c) acc += xr[c] * ip_w[tid * C_IN_ + c];
    hl[tid] = acc;
  }
  ul[tid] = u_last[b * 256 + tid];
  __syncthreads();
  {
    float acc = 0.f;
    const float4* wv = (const float4*)(in_proj_w + (size_t)(256 + tid) * 128);
    const float4* h4 = (const float4*)hl;
    for (int k = 0; k < 32; ++k) {
      float4 a = wv[k], c = h4[k];
      acc += c.x * a.x + c.y * a.y + c.z * a.z + c.w * a.w;
    }
    zs[tid] = silu_f(acc);
  }
  if (tid < 16) {
    float acc = 0.f;
    const float4* wv = (const float4*)(x_proj_w + (size_t)(24 + tid) * 256);
    const float4* u4 = (const float4*)ul;
    for (int k = 0; k < 64; ++k) {
      float4 a = wv[k], c = u4[k];
      acc += c.x * a.x + c.y * a.y + c.z * a.z + c.w * a.w;
    }
    cm[tid] = acc;
  }
  __syncthreads();
  {
    const float* st = state + ((size_t)b * 256 + tid) * 16;
    float acc = 0.f;
#pragma unroll
    for (int n = 0; n < 16; ++n) acc += st[n] * cm[n];
    yv[tid] = (acc + ul[tid] * D_skip[tid]) * zs[tid];
  }
  __syncthreads();
  if (tid < 128) {
    float acc = 0.f;
    const float4* wv = (const float4*)(out_proj_w + (size_t)tid * 256);
    const float4* y4 = (const float4*)yv;
    for (int k = 0; k < 64; ++k) {
      float4 a = wv[k], c = y4[k];
      acc += c.x * a.x + c.y * a.y + c.z * a.z + c.w * a.w;
    }
    ov[tid] = acc;
  }
  __syncthreads();
  if (tid < 64) {
    float acc = fc1_b[tid];
    const float4* wv = (const float4*)(fc1_w + (size_t)tid * 128);
    const float4* o4 = (const float4*)ov;
    for (int k = 0; k < 32; ++k) {
      float4 a = wv[k], c = o4[k];
      acc += c.x * a.x + c.y * a.y + c.z * a.z + c.w * a.w;
    }
    hid[tid] = fmaxf(acc, 0.f);
  }
  __syncthreads();
  if (tid < N_CLS) {
    float acc = fc2_b[tid];
    const float* wv = fc2_w + (size_t)tid * 64;
    for (int k = 0; k < 64; ++k) acc += hid[k] * wv[k];
    out[b * N_CLS + tid] = acc;
  }
}

extern "C" void kernel_launch(void* const* d_in, const int* in_sizes, int n_in,
                              void* d_out, int out_size, void* d_ws, size_t ws_size,
                              hipStream_t stream) {
  (void)in_sizes; (void)n_in; (void)out_size; (void)ws_size;
  const float* x         = (const float*)d_in[0];
  const float* ip_w      = (const float*)d_in[1];
  const float* ip_b      = (const float*)d_in[2];
  const float* in_proj_w = (const float*)d_in[3];
  const float* conv_w    = (const float*)d_in[4];
  const float* conv_b    = (const float*)d_in[5];
  const float* x_proj_w  = (const float*)d_in[6];
  const float* dt_proj_w = (const float*)d_in[7];
  const float* dt_proj_b = (const float*)d_in[8];
  const float* A_log     = (const float*)d_in[9];
  const float* D_skip    = (const float*)d_in[10];
  const float* out_proj_w= (const float*)d_in[11];
  const float* fc1_w     = (const float*)d_in[12];
  const float* fc1_b     = (const float*)d_in[13];
  const float* fc2_w     = (const float*)d_in[14];
  const float* fc2_b     = (const float*)d_in[15];
  float* out = (float*)d_out;

  float* u       = (float*)d_ws;                 // 16,384,000 f32 (65.5 MB)
  float* delta_T = u + (size_t)16384000;         // 16,384,000 f32 [b][256][1000]
  float* du_T    = delta_T + (size_t)16384000;   // 16,384,000 f32 [b][256][1000]
  float* pk_bm   = du_T + (size_t)16384000;      //  1,024,000 f32 [b][250][16][4]
  float* state   = pk_bm + (size_t)1024000;      //    262,144 f32
  float* u_last  = state + (size_t)262144;       //     16,384 f32 (201.8 MB, proven)
  // aliases into regions dead at their use time (proven pattern):
  char* h_pk = (char*)delta_T;                   // k0..k1 (delta_T written later by k3)
  char* w_pk = h_pk + (size_t)64 * 64 * 4096;
  float* Qb  = u;                                // k4..k4b (u dead after k3)
  float* Pb  = u + (size_t)4000000;

  k0_prep<<<dim3(17, 64), 256, 0, stream>>>(x, ip_w, ip_b, in_proj_w, h_pk, w_pk);
  k1_u<<<dim3(16, 64), 256, 0, stream>>>(h_pk, w_pk, conv_w, conv_b, u);
  k3_delta<<<1000, 256, 0, stream>>>(u, x_proj_w, dt_proj_w, dt_proj_b,
                                     delta_T, du_T, pk_bm, u_last);
  k4_scan<<<dim3(16, 64, NCH), 256, 0, stream>>>(delta_T, du_T, pk_bm, A_log, Qb, Pb);
  k4b_combine<<<1024, 256, 0, stream>>>(Qb, Pb, state);
  k5_head<<<64, 256, 0, stream>>>(x, ip_w, ip_b, in_proj_w, x_proj_w, u_last, state,
                                  D_skip, out_proj_w, fc1_w, fc1_b, fc2_w, fc2_b, out);
}